// Round 11
// baseline (290.869 us; speedup 1.0000x reference)
//
#include <hip/hip_runtime.h>

#define N 9216
#define CIN 256
#define DQ 32
#define NT 144                      // N / 64 (n-chunk count)
#define LOG2E 1.44269504088896340736f

typedef short short8 __attribute__((ext_vector_type(8)));   // 8 bf16 in 4 VGPRs
typedef float floatx4 __attribute__((ext_vector_type(4)));
typedef unsigned short ushort_t;

__device__ __forceinline__ ushort_t f2bf(float f) {
  union { float f; unsigned u; } a; a.f = f;
  unsigned u = a.u;
  u += 0x7fffu + ((u >> 16) & 1u);   // round-to-nearest-even
  return (ushort_t)(u >> 16);
}
// cheap round-to-nearest: 2 VALU ops instead of 5.
__device__ __forceinline__ ushort_t f2bf_fast(float f) {
  union { float f; unsigned u; } a; a.f = f;
  return (ushort_t)((a.u + 0x8000u) >> 16);
}
__device__ __forceinline__ float bf2f(ushort_t h) {
  union { unsigned u; float f; } a; a.u = ((unsigned)h) << 16;
  return a.f;
}
// pack two floats -> one uint of 2 bf16 (lo in [15:0], hi in [31:16])
__device__ __forceinline__ unsigned pack2(float lo, float hi) {
  return ((unsigned)f2bf_fast(hi) << 16) | (unsigned)f2bf_fast(lo);
}
// 8 consecutive fp32 -> bf16x8 A-fragment
__device__ __forceinline__ short8 mk_bf16x8(const float* p) {
  float4 f0 = *(const float4*)(p);
  float4 f1 = *(const float4*)(p + 4);
  union { unsigned u[4]; short8 v; } r;
  r.u[0] = pack2(f0.x, f0.y);
  r.u[1] = pack2(f0.z, f0.w);
  r.u[2] = pack2(f1.x, f1.y);
  r.u[3] = pack2(f1.z, f1.w);
  return r.v;
}

// ---------------------------------------------------------------------------
// Shared staging: x tile (256 c x 64 n) -> LDS bf16 xbT[n][k=c].
// ---------------------------------------------------------------------------
#define XBT_STRIDE 264   // ushorts per row (256 + 8 pad); 132 uints

__device__ __forceinline__ void stage_x_tile(
    const float* __restrict__ x, int n0, int t, ushort_t (*xbT)[XBT_STRIDE])
{
  const int p = t & 31, ng = t >> 5;          // ng in [0,8)
  unsigned* base = (unsigned*)&xbT[0][0] + (size_t)(ng * 8) * 132;
#pragma unroll
  for (int cc = 0; cc < 4; ++cc) {
    const int c = cc * 64 + 2 * p;
    const float* r0 = x + (size_t)c * N + n0 + ng * 8;
    const float* r1 = r0 + N;
    float4 a0 = *(const float4*)(r0);
    float4 a1 = *(const float4*)(r0 + 4);
    float4 b0 = *(const float4*)(r1);
    float4 b1 = *(const float4*)(r1 + 4);
    unsigned* d = base + (cc * 32 + p);
    d[0 * 132] = pack2(a0.x, b0.x);
    d[1 * 132] = pack2(a0.y, b0.y);
    d[2 * 132] = pack2(a0.z, b0.z);
    d[3 * 132] = pack2(a0.w, b0.w);
    d[4 * 132] = pack2(a1.x, b1.x);
    d[5 * 132] = pack2(a1.y, b1.y);
    d[6 * 132] = pack2(a1.z, b1.z);
    d[7 * 132] = pack2(a1.w, b1.w);
  }
}

// ---------------------------------------------------------------------------
// Kernel 1: q/k/v projections via bf16 MFMA.  UNCHANGED (control).
// ---------------------------------------------------------------------------
__global__ __launch_bounds__(256) void qkv_mfma(
    const float* __restrict__ x,
    const float* __restrict__ Wq, const float* __restrict__ bq,
    const float* __restrict__ Wk, const float* __restrict__ bk,
    const float* __restrict__ Wv, const float* __restrict__ bv,
    ushort_t* __restrict__ qT, ushort_t* __restrict__ kT,
    ushort_t* __restrict__ vG, float* __restrict__ sumExp)
{
  if (blockIdx.x == 0 && blockIdx.y == 0 && threadIdx.x == 0) *sumExp = 0.f;

  __shared__ ushort_t xbT[64][XBT_STRIDE];
  const int t = threadIdx.x;
  const int n0 = blockIdx.x * 64;
  const int oc = blockIdx.y;                 // 0: q(32)+k(32); 1..4: v
  const int w = t >> 6, lane = t & 63;
  const int quad = lane >> 4, l15 = lane & 15;

  stage_x_tile(x, n0, t, xbT);
  __syncthreads();

  const int obase = oc * 64 + w * 16;
  const int oA = obase + l15;                // A-frag row (m = l15)
  const float* Arow;
  if (oc == 0) Arow = (obase < 32) ? (Wq + (size_t)oA * CIN)
                                   : (Wk + (size_t)(oA - 32) * CIN);
  else         Arow = Wv + (size_t)(oA - 64) * CIN;

  floatx4 acc[4];
#pragma unroll
  for (int b2 = 0; b2 < 4; ++b2) acc[b2] = (floatx4){0.f, 0.f, 0.f, 0.f};

#pragma unroll
  for (int ks = 0; ks < 8; ++ks) {
    const short8 af = mk_bf16x8(Arow + ks * 32 + 8 * quad);
#pragma unroll
    for (int b2 = 0; b2 < 4; ++b2) {
      const short8 bf = *(const short8*)&xbT[b2 * 16 + l15][ks * 32 + 8 * quad];
      acc[b2] = __builtin_amdgcn_mfma_f32_16x16x32_bf16(af, bf, acc[b2], 0, 0, 0);
    }
  }

#pragma unroll
  for (int b2 = 0; b2 < 4; ++b2) {
    const int n = n0 + b2 * 16 + l15;
#pragma unroll
    for (int r = 0; r < 4; ++r) {
      const int o = obase + 4 * quad + r;
      const float val = acc[b2][r];
      if (oc == 0) {
        if (o < 32) qT[(size_t)n * DQ + o]        = f2bf((val + bq[o]) * LOG2E);
        else        kT[(size_t)n * DQ + (o - 32)] = f2bf(val + bk[o - 32]);
      } else        vG[(size_t)(o - 64) * N + n]  = f2bf(val + bv[o - 64]);
    }
  }
}

// ---------------------------------------------------------------------------
// Kernel 2: flash attention, BARRIER-FREE self-contained waves.
// R10 post-mortem: V-BW dedup was neutral -> limiter is unhidden latency +
// per-iter 4-wave barrier convoy.  This version: each wave owns 32 n x 128 c
// and is fully independent (no __syncthreads, no LDS buffer).
//   S^T = K * Q^T   (K as A-op, Q as B-op) -> P lands with n in lane columns
//   P C-layout -> PV B-layout via 16 ds_bpermute + 8 cndmask (in-register;
//     dest lane (q,l15) slot jj <- src lane ((q&1)*2+(jj>>1))*16+l15,
//     pkA/pkB by jj&1, s-tile by q>>1)
//   O^T += V * P  with V A-frags direct from global (L1-shared across waves)
// K prefetched one iter ahead (no barrier ever drains vmcnt).
// acc[8][2] = 64 AGPR; ~85 VGPR -> launch_bounds(256,3) caps 170, no spill.
// Wave w of block: n-half (w>>1)*32, c-half (w&1)*128.  Grid (144, nsl=5)
// = 720 blocks on 768 slots (94% single round).
// ---------------------------------------------------------------------------
__global__ __launch_bounds__(256, 3) void attn_kernel(
    const ushort_t* __restrict__ qT, const ushort_t* __restrict__ kT,
    const ushort_t* __restrict__ vG,
    ushort_t* __restrict__ Opart, float* __restrict__ lpart,
    int base, int rem)
{
  const int t = threadIdx.x;
  const int w = t >> 6;
  const int lane = t & 63;
  const int quad = lane >> 4;
  const int l15 = lane & 15;
  const int nt = blockIdx.x;
  const int s  = blockIdx.y;
  const int n0 = nt * 64;
  const int sliceIters = base + (s < rem ? 1 : 0);
  const int it0 = s * base + (s < rem ? s : rem);
  const int nw = (w >> 1) * 32;         // n-offset of this wave
  const int c0 = (w & 1) * 128;         // c-offset of this wave

  // Q B-frags (loop-invariant): B[k=c=8*quad+j][n=l15]
  short8 aq0 = *(const short8*)(qT + (size_t)(n0 + nw + l15) * DQ + 8 * quad);
  short8 aq1 = *(const short8*)(qT + (size_t)(n0 + nw + 16 + l15) * DQ + 8 * quad);

  floatx4 acc[8][2];
#pragma unroll
  for (int ct = 0; ct < 8; ++ct)
#pragma unroll
    for (int u = 0; u < 2; ++u)
      acc[ct][u] = (floatx4){0.f, 0.f, 0.f, 0.f};
  float lsum0 = 0.f, lsum1 = 0.f;
  const floatx4 z4 = {0.f, 0.f, 0.f, 0.f};

  // bpermute source addresses (lane*4): src quads (q&1)*2 and (q&1)*2+1
  const int a0 = (((quad & 1) << 5) + l15) << 2;
  const int a1 = a0 + 64;
  const bool hi = (quad >= 2);          // s-tile select (m >= 16)

  int m0 = it0 * 32;
  // K A-frags: A[m-row=l15][k=c=8*quad+j]
  short8 kb0 = *(const short8*)(kT + (size_t)(m0 + l15) * DQ + 8 * quad);
  short8 kb1 = *(const short8*)(kT + (size_t)(m0 + 16 + l15) * DQ + 8 * quad);

  for (int it = 0; it < sliceIters; ++it) {
    const int mN = (it + 1 < sliceIters) ? (m0 + 32) : m0;

    // V A-frags for this iter: A[c-row=l15][k=m=8*quad+j], 16B/lane.
    const ushort_t* vb = vG + (size_t)m0 + 8 * quad;
    short8 av0 = *(const short8*)(vb + (size_t)(c0 +   0 + l15) * N);
    short8 av1 = *(const short8*)(vb + (size_t)(c0 +  16 + l15) * N);
    short8 av2 = *(const short8*)(vb + (size_t)(c0 +  32 + l15) * N);
    short8 av3 = *(const short8*)(vb + (size_t)(c0 +  48 + l15) * N);
    short8 av4 = *(const short8*)(vb + (size_t)(c0 +  64 + l15) * N);
    short8 av5 = *(const short8*)(vb + (size_t)(c0 +  80 + l15) * N);
    short8 av6 = *(const short8*)(vb + (size_t)(c0 +  96 + l15) * N);
    short8 av7 = *(const short8*)(vb + (size_t)(c0 + 112 + l15) * N);

    // prefetch next iter's K (fully hidden: ~1 iter of slack, no barrier)
    short8 kb0n = *(const short8*)(kT + (size_t)(mN + l15) * DQ + 8 * quad);
    short8 kb1n = *(const short8*)(kT + (size_t)(mN + 16 + l15) * DQ + 8 * quad);

    // S^T tiles: D[m-row=4*quad+r (+16t)][n-col=l15 (+16u)]
    floatx4 s00 = __builtin_amdgcn_mfma_f32_16x16x32_bf16(kb0, aq0, z4, 0, 0, 0);
    floatx4 s10 = __builtin_amdgcn_mfma_f32_16x16x32_bf16(kb1, aq0, z4, 0, 0, 0);
    floatx4 s01 = __builtin_amdgcn_mfma_f32_16x16x32_bf16(kb0, aq1, z4, 0, 0, 0);
    floatx4 s11 = __builtin_amdgcn_mfma_f32_16x16x32_bf16(kb1, aq1, z4, 0, 0, 0);

    // exp2 (q pre-scaled by log2e) + sumexp + pack
    float e000 = exp2f(s00[0]), e001 = exp2f(s00[1]);
    float e002 = exp2f(s00[2]), e003 = exp2f(s00[3]);
    float e100 = exp2f(s10[0]), e101 = exp2f(s10[1]);
    float e102 = exp2f(s10[2]), e103 = exp2f(s10[3]);
    float e010 = exp2f(s01[0]), e011 = exp2f(s01[1]);
    float e012 = exp2f(s01[2]), e013 = exp2f(s01[3]);
    float e110 = exp2f(s11[0]), e111 = exp2f(s11[1]);
    float e112 = exp2f(s11[2]), e113 = exp2f(s11[3]);
    lsum0 += (e000 + e001) + (e002 + e003) + (e100 + e101) + (e102 + e103);
    lsum1 += (e010 + e011) + (e012 + e013) + (e110 + e111) + (e112 + e113);

    // u = 0 transform
    unsigned pA0 = pack2(e000, e001), pB0 = pack2(e002, e003);
    unsigned pA1 = pack2(e100, e101), pB1 = pack2(e102, e103);
    int v0a = __builtin_amdgcn_ds_bpermute(a0, (int)pA0);
    int v0b = __builtin_amdgcn_ds_bpermute(a0, (int)pA1);
    int v1a = __builtin_amdgcn_ds_bpermute(a0, (int)pB0);
    int v1b = __builtin_amdgcn_ds_bpermute(a0, (int)pB1);
    int v2a = __builtin_amdgcn_ds_bpermute(a1, (int)pA0);
    int v2b = __builtin_amdgcn_ds_bpermute(a1, (int)pA1);
    int v3a = __builtin_amdgcn_ds_bpermute(a1, (int)pB0);
    int v3b = __builtin_amdgcn_ds_bpermute(a1, (int)pB1);
    union { int i[4]; short8 v; } pf0u;
    pf0u.i[0] = hi ? v0b : v0a;
    pf0u.i[1] = hi ? v1b : v1a;
    pf0u.i[2] = hi ? v2b : v2a;
    pf0u.i[3] = hi ? v3b : v3a;
    const short8 pf0 = pf0u.v;

    // u = 1 transform
    unsigned qA0 = pack2(e010, e011), qB0 = pack2(e012, e013);
    unsigned qA1 = pack2(e110, e111), qB1 = pack2(e112, e113);
    int u0a = __builtin_amdgcn_ds_bpermute(a0, (int)qA0);
    int u0b = __builtin_amdgcn_ds_bpermute(a0, (int)qA1);
    int u1a = __builtin_amdgcn_ds_bpermute(a0, (int)qB0);
    int u1b = __builtin_amdgcn_ds_bpermute(a0, (int)qB1);
    int u2a = __builtin_amdgcn_ds_bpermute(a1, (int)qA0);
    int u2b = __builtin_amdgcn_ds_bpermute(a1, (int)qA1);
    int u3a = __builtin_amdgcn_ds_bpermute(a1, (int)qB0);
    int u3b = __builtin_amdgcn_ds_bpermute(a1, (int)qB1);
    union { int i[4]; short8 v; } pf1u;
    pf1u.i[0] = hi ? u0b : u0a;
    pf1u.i[1] = hi ? u1b : u1a;
    pf1u.i[2] = hi ? u2b : u2a;
    pf1u.i[3] = hi ? u3b : u3a;
    const short8 pf1 = pf1u.v;

    // O^T += V * P
    acc[0][0] = __builtin_amdgcn_mfma_f32_16x16x32_bf16(av0, pf0, acc[0][0], 0, 0, 0);
    acc[1][0] = __builtin_amdgcn_mfma_f32_16x16x32_bf16(av1, pf0, acc[1][0], 0, 0, 0);
    acc[2][0] = __builtin_amdgcn_mfma_f32_16x16x32_bf16(av2, pf0, acc[2][0], 0, 0, 0);
    acc[3][0] = __builtin_amdgcn_mfma_f32_16x16x32_bf16(av3, pf0, acc[3][0], 0, 0, 0);
    acc[4][0] = __builtin_amdgcn_mfma_f32_16x16x32_bf16(av4, pf0, acc[4][0], 0, 0, 0);
    acc[5][0] = __builtin_amdgcn_mfma_f32_16x16x32_bf16(av5, pf0, acc[5][0], 0, 0, 0);
    acc[6][0] = __builtin_amdgcn_mfma_f32_16x16x32_bf16(av6, pf0, acc[6][0], 0, 0, 0);
    acc[7][0] = __builtin_amdgcn_mfma_f32_16x16x32_bf16(av7, pf0, acc[7][0], 0, 0, 0);
    acc[0][1] = __builtin_amdgcn_mfma_f32_16x16x32_bf16(av0, pf1, acc[0][1], 0, 0, 0);
    acc[1][1] = __builtin_amdgcn_mfma_f32_16x16x32_bf16(av1, pf1, acc[1][1], 0, 0, 0);
    acc[2][1] = __builtin_amdgcn_mfma_f32_16x16x32_bf16(av2, pf1, acc[2][1], 0, 0, 0);
    acc[3][1] = __builtin_amdgcn_mfma_f32_16x16x32_bf16(av3, pf1, acc[3][1], 0, 0, 0);
    acc[4][1] = __builtin_amdgcn_mfma_f32_16x16x32_bf16(av4, pf1, acc[4][1], 0, 0, 0);
    acc[5][1] = __builtin_amdgcn_mfma_f32_16x16x32_bf16(av5, pf1, acc[5][1], 0, 0, 0);
    acc[6][1] = __builtin_amdgcn_mfma_f32_16x16x32_bf16(av6, pf1, acc[6][1], 0, 0, 0);
    acc[7][1] = __builtin_amdgcn_mfma_f32_16x16x32_bf16(av7, pf1, acc[7][1], 0, 0, 0);

    kb0 = kb0n; kb1 = kb1n; m0 = mN;
  }

  // sumexp: reduce across quads (xor 16, 32) -> full m coverage per (u, l15)
  lsum0 += __shfl_xor(lsum0, 16);
  lsum0 += __shfl_xor(lsum0, 32);
  lsum1 += __shfl_xor(lsum1, 16);
  lsum1 += __shfl_xor(lsum1, 32);
  if ((w & 1) == 0 && quad == 0) {
    lpart[(size_t)s * N + n0 + nw + l15]      = lsum0;
    lpart[(size_t)s * N + n0 + nw + 16 + l15] = lsum1;
  }

  // store O^T partial, layout [s][nt64][c:256][n:64] (cco-compatible)
  const size_t basep = ((size_t)s * NT + nt) * 256;
#pragma unroll
  for (int ct = 0; ct < 8; ++ct)
#pragma unroll
    for (int u = 0; u < 2; ++u)
#pragma unroll
      for (int r = 0; r < 4; ++r) {
        const int c  = c0 + ct * 16 + 4 * quad + r;
        const int nl = nw + u * 16 + l15;
        Opart[(basep + c) * 64 + nl] = f2bf(acc[ct][u][r]);
      }
}

// ---------------------------------------------------------------------------
// Kernel 3: fused combine + gate-exp.  UNCHANGED (control).
// ---------------------------------------------------------------------------
template<int NSL>
__global__ __launch_bounds__(1024) void cco_kernel(
    const ushort_t* __restrict__ Opart, const float* __restrict__ lpart,
    float* __restrict__ e_buf, float* __restrict__ sumExp)
{
  const int nt = blockIdx.x;
  const int t = threadIdx.x;
  const int n = t & 63, ci = t >> 6;   // ci in [0,16)
  float mx = -3.4e38f, sm = 0.f;
#pragma unroll
  for (int k = 0; k < 16; ++k) {
    const int c = ci * 16 + k;
    float val = 0.f;
#pragma unroll
    for (int s2 = 0; s2 < NSL; ++s2)
      val += bf2f(Opart[(((size_t)s2 * NT + nt) * 256 + c) * 64 + n]);
    mx = fmaxf(mx, val);
    sm += val;
  }
  __shared__ float rmx[16][64], rsm[16][64];
  rmx[ci][n] = mx; rsm[ci][n] = sm;
  __syncthreads();
  if (t < 64) {
    float m = rmx[0][t], s = rsm[0][t];
#pragma unroll
    for (int g = 1; g < 16; ++g) { m = fmaxf(m, rmx[g][t]); s += rsm[g][t]; }
    float l = 0.f;
#pragma unroll
    for (int s3 = 0; s3 < NSL; ++s3) l += lpart[(size_t)s3 * N + nt * 64 + t];
    const float oc = (m + s * (1.0f / 256.0f)) / l;
    const float ev = exp2f(oc * (0.0625f * LOG2E));
    e_buf[nt * 64 + t] = ev;
    float vs = ev;
    vs += __shfl_xor(vs, 1);  vs += __shfl_xor(vs, 2);
    vs += __shfl_xor(vs, 4);  vs += __shfl_xor(vs, 8);
    vs += __shfl_xor(vs, 16); vs += __shfl_xor(vs, 32);
    if (t == 0) atomicAdd(sumExp, vs);
  }
}

// ---------------------------------------------------------------------------
// Kernel 4: final 1x1 conv via bf16 MFMA + fp32 epilogue.  UNCHANGED.
// ---------------------------------------------------------------------------
__global__ __launch_bounds__(256) void final_mfma(
    const float* __restrict__ x, const float* __restrict__ W6,
    const float* __restrict__ b6, const float* __restrict__ gamma,
    const float* __restrict__ e_buf, const float* __restrict__ sumExp,
    float* __restrict__ out)
{
  __shared__ ushort_t xbT[64][XBT_STRIDE];
  const int t = threadIdx.x;
  const int n0 = blockIdx.x * 64;
  const int w = t >> 6, lane = t & 63;
  const int quad = lane >> 4, l15 = lane & 15;

  stage_x_tile(x, n0, t, xbT);
  __syncthreads();

  const int obase = blockIdx.y * 64 + w * 16;
  const float* Arow = W6 + (size_t)(obase + l15) * CIN;

  floatx4 acc[4];
#pragma unroll
  for (int b2 = 0; b2 < 4; ++b2) acc[b2] = (floatx4){0.f, 0.f, 0.f, 0.f};

#pragma unroll
  for (int ks = 0; ks < 8; ++ks) {
    const short8 af = mk_bf16x8(Arow + ks * 32 + 8 * quad);
#pragma unroll
    for (int b2 = 0; b2 < 4; ++b2) {
      const short8 bf = *(const short8*)&xbT[b2 * 16 + l15][ks * 32 + 8 * quad];
      acc[b2] = __builtin_amdgcn_mfma_f32_16x16x32_bf16(af, bf, acc[b2], 0, 0, 0);
    }
  }

  const float g1 = 1.0f + gamma[0];
  const float inv = 1.0f / sumExp[0];
#pragma unroll
  for (int b2 = 0; b2 < 4; ++b2) {
    const int n = n0 + b2 * 16 + l15;
    const float xc = e_buf[n] * inv;
#pragma unroll
    for (int r = 0; r < 4; ++r) {
      const int o = obase + 4 * quad + r;
      const float xv = x[(size_t)o * N + n];
      out[(size_t)o * N + n] = xv + g1 * (xc * acc[b2][r] + b6[o]);
    }
  }
}

// ---------------------------------------------------------------------------
extern "C" void kernel_launch(void* const* d_in, const int* in_sizes, int n_in,
                              void* d_out, int out_size, void* d_ws, size_t ws_size,
                              hipStream_t stream)
{
  const float* x     = (const float*)d_in[0];
  const float* Wq    = (const float*)d_in[1];
  const float* bq    = (const float*)d_in[2];
  const float* Wk    = (const float*)d_in[3];
  const float* bk    = (const float*)d_in[4];
  const float* Wv    = (const float*)d_in[5];
  const float* bv    = (const float*)d_in[6];
  const float* W6    = (const float*)d_in[7];
  const float* b6    = (const float*)d_in[8];
  const float* gamma = (const float*)d_in[9];
  float* out = (float*)d_out;

  // nsl = 5: 720 attn blocks on 768 slots (3 blocks/CU at launch_bounds(256,3)).
  const size_t fixed = (size_t)N * DQ * 2 * 2        // qT,kT
                     + (size_t)CIN * N * 2            // vG
                     + (size_t)N * 4                  // e_buf
                     + 256;                           // sumExp (+pad)
  int nsl = 5;
  size_t need = fixed + (size_t)nsl * NT * 256 * 64 * 2 + (size_t)nsl * N * 4;
  if (ws_size < need) nsl = 4;
  const int totIters = N / 32;                        // 288
  const int base = totIters / nsl;
  const int rem  = totIters % nsl;

  char* ws = (char*)d_ws;
  const size_t OFF_QT = 0;
  const size_t OFF_KT = OFF_QT + (size_t)N * DQ * 2;
  const size_t OFF_V  = OFF_KT + (size_t)N * DQ * 2;
  const size_t OFF_OP = OFF_V  + (size_t)CIN * N * 2;
  const size_t OFF_LP = OFF_OP + (size_t)nsl * NT * 256 * 64 * 2;
  const size_t OFF_EB = OFF_LP + (size_t)nsl * N * 4;
  const size_t OFF_SE = OFF_EB + (size_t)N * 4;

  ushort_t* qT     = (ushort_t*)(ws + OFF_QT);
  ushort_t* kT     = (ushort_t*)(ws + OFF_KT);
  ushort_t* vG     = (ushort_t*)(ws + OFF_V);
  ushort_t* Opart  = (ushort_t*)(ws + OFF_OP);
  float*    lpart  = (float*)(ws + OFF_LP);
  float*    e_buf  = (float*)(ws + OFF_EB);
  float*    sumExp = (float*)(ws + OFF_SE);

  qkv_mfma<<<dim3(NT, 5), 256, 0, stream>>>(x, Wq, bq, Wk, bk, Wv, bv, qT, kT, vG, sumExp);
  attn_kernel<<<dim3(NT, nsl), 256, 0, stream>>>(qT, kT, vG, Opart, lpart, base, rem);
  if (nsl == 5) cco_kernel<5><<<NT, 1024, 0, stream>>>(Opart, lpart, e_buf, sumExp);
  else          cco_kernel<4><<<NT, 1024, 0, stream>>>(Opart, lpart, e_buf, sumExp);
  final_mfma<<<dim3(NT, 4), 256, 0, stream>>>(x, W6, b6, gamma, e_buf, sumExp, out);
}

// Round 12
// 234.924 us; speedup vs baseline: 1.2381x; 1.2381x over previous
//
#include <hip/hip_runtime.h>

#define N 9216
#define CIN 256
#define DQ 32
#define NT 144                      // N / 64 (n-chunk count)
#define LOG2E 1.44269504088896340736f

typedef short short8 __attribute__((ext_vector_type(8)));   // 8 bf16 in 4 VGPRs
typedef float floatx4 __attribute__((ext_vector_type(4)));
typedef unsigned short ushort_t;

__device__ __forceinline__ ushort_t f2bf(float f) {
  union { float f; unsigned u; } a; a.f = f;
  unsigned u = a.u;
  u += 0x7fffu + ((u >> 16) & 1u);   // round-to-nearest-even
  return (ushort_t)(u >> 16);
}
// cheap round-to-nearest: 2 VALU ops instead of 5.
__device__ __forceinline__ ushort_t f2bf_fast(float f) {
  union { float f; unsigned u; } a; a.f = f;
  return (ushort_t)((a.u + 0x8000u) >> 16);
}
__device__ __forceinline__ float bf2f(ushort_t h) {
  union { unsigned u; float f; } a; a.u = ((unsigned)h) << 16;
  return a.f;
}
// pack two floats -> one uint of 2 bf16 (lo in [15:0], hi in [31:16])
__device__ __forceinline__ unsigned pack2(float lo, float hi) {
  return ((unsigned)f2bf_fast(hi) << 16) | (unsigned)f2bf_fast(lo);
}
// 8 consecutive fp32 -> bf16x8 A-fragment
__device__ __forceinline__ short8 mk_bf16x8(const float* p) {
  float4 f0 = *(const float4*)(p);
  float4 f1 = *(const float4*)(p + 4);
  union { unsigned u[4]; short8 v; } r;
  r.u[0] = pack2(f0.x, f0.y);
  r.u[1] = pack2(f0.z, f0.w);
  r.u[2] = pack2(f1.x, f1.y);
  r.u[3] = pack2(f1.z, f1.w);
  return r.v;
}

// ---------------------------------------------------------------------------
// Shared staging: x tile (256 c x 64 n) -> LDS bf16 xbT[n][k=c].
// ---------------------------------------------------------------------------
#define XBT_STRIDE 264   // ushorts per row (256 + 8 pad); 132 uints

__device__ __forceinline__ void stage_x_tile(
    const float* __restrict__ x, int n0, int t, ushort_t (*xbT)[XBT_STRIDE])
{
  const int p = t & 31, ng = t >> 5;          // ng in [0,8)
  unsigned* base = (unsigned*)&xbT[0][0] + (size_t)(ng * 8) * 132;
#pragma unroll
  for (int cc = 0; cc < 4; ++cc) {
    const int c = cc * 64 + 2 * p;
    const float* r0 = x + (size_t)c * N + n0 + ng * 8;
    const float* r1 = r0 + N;
    float4 a0 = *(const float4*)(r0);
    float4 a1 = *(const float4*)(r0 + 4);
    float4 b0 = *(const float4*)(r1);
    float4 b1 = *(const float4*)(r1 + 4);
    unsigned* d = base + (cc * 32 + p);
    d[0 * 132] = pack2(a0.x, b0.x);
    d[1 * 132] = pack2(a0.y, b0.y);
    d[2 * 132] = pack2(a0.z, b0.z);
    d[3 * 132] = pack2(a0.w, b0.w);
    d[4 * 132] = pack2(a1.x, b1.x);
    d[5 * 132] = pack2(a1.y, b1.y);
    d[6 * 132] = pack2(a1.z, b1.z);
    d[7 * 132] = pack2(a1.w, b1.w);
  }
}

// ---------------------------------------------------------------------------
// Kernel 1: q/k/v projections via bf16 MFMA.  UNCHANGED (control).
// ---------------------------------------------------------------------------
__global__ __launch_bounds__(256) void qkv_mfma(
    const float* __restrict__ x,
    const float* __restrict__ Wq, const float* __restrict__ bq,
    const float* __restrict__ Wk, const float* __restrict__ bk,
    const float* __restrict__ Wv, const float* __restrict__ bv,
    ushort_t* __restrict__ qT, ushort_t* __restrict__ kT,
    ushort_t* __restrict__ vG, float* __restrict__ sumExp)
{
  if (blockIdx.x == 0 && blockIdx.y == 0 && threadIdx.x == 0) *sumExp = 0.f;

  __shared__ ushort_t xbT[64][XBT_STRIDE];
  const int t = threadIdx.x;
  const int n0 = blockIdx.x * 64;
  const int oc = blockIdx.y;                 // 0: q(32)+k(32); 1..4: v
  const int w = t >> 6, lane = t & 63;
  const int quad = lane >> 4, l15 = lane & 15;

  stage_x_tile(x, n0, t, xbT);
  __syncthreads();

  const int obase = oc * 64 + w * 16;
  const int oA = obase + l15;                // A-frag row (m = l15)
  const float* Arow;
  if (oc == 0) Arow = (obase < 32) ? (Wq + (size_t)oA * CIN)
                                   : (Wk + (size_t)(oA - 32) * CIN);
  else         Arow = Wv + (size_t)(oA - 64) * CIN;

  floatx4 acc[4];
#pragma unroll
  for (int b2 = 0; b2 < 4; ++b2) acc[b2] = (floatx4){0.f, 0.f, 0.f, 0.f};

#pragma unroll
  for (int ks = 0; ks < 8; ++ks) {
    const short8 af = mk_bf16x8(Arow + ks * 32 + 8 * quad);
#pragma unroll
    for (int b2 = 0; b2 < 4; ++b2) {
      const short8 bf = *(const short8*)&xbT[b2 * 16 + l15][ks * 32 + 8 * quad];
      acc[b2] = __builtin_amdgcn_mfma_f32_16x16x32_bf16(af, bf, acc[b2], 0, 0, 0);
    }
  }

#pragma unroll
  for (int b2 = 0; b2 < 4; ++b2) {
    const int n = n0 + b2 * 16 + l15;
#pragma unroll
    for (int r = 0; r < 4; ++r) {
      const int o = obase + 4 * quad + r;
      const float val = acc[b2][r];
      if (oc == 0) {
        if (o < 32) qT[(size_t)n * DQ + o]        = f2bf((val + bq[o]) * LOG2E);
        else        kT[(size_t)n * DQ + (o - 32)] = f2bf(val + bk[o - 32]);
      } else        vG[(size_t)(o - 64) * N + n]  = f2bf(val + bv[o - 64]);
    }
  }
}

// ---------------------------------------------------------------------------
// Kernel 2: flash attention — REVERTED to the proven R6-R8 structure
// (64n x 4 waves, LDS P round-trip, 115 us; R11's bpermute version hit 5.3M
// LDS bank conflicts and regressed to 195 us).  NEW: split into two PHASES
// over the K-loop so each dispatch is ~60 us — this unblinds the top-5 table
// (attn replays at 115 us were hiding a ~70-80 us unexplained residual in
// the non-attn stack).  Phase 0: first half of iters, store partial acc/lsum.
// Phase 1: reload partials, finish, store.  Identical total work + one extra
// Opart round-trip (~2-3 us).
// ---------------------------------------------------------------------------
__global__ __launch_bounds__(256, 4) void attn_kernel(
    const ushort_t* __restrict__ qT, const ushort_t* __restrict__ kT,
    const ushort_t* __restrict__ vG,
    ushort_t* __restrict__ Opart, float* __restrict__ lpart,
    int base, int rem, int phase)
{
  __shared__ ushort_t Pb[2][64][36];    // double-buffered P tile (64n x 32m)

  const int t = threadIdx.x;
  const int w = t >> 6;
  const int lane = t & 63;
  const int quad = lane >> 4;
  const int l15 = lane & 15;
  const int nt = blockIdx.x;
  const int s  = blockIdx.y;
  const int n0 = nt * 64;
  const int sliceIters = base + (s < rem ? 1 : 0);
  const int it0 = s * base + (s < rem ? s : rem);
  const int mbase = it0 * 32;
  const int cw = w * 64;

  const int half  = (sliceIters + 1) >> 1;
  const int itBeg = phase ? half : 0;
  const int itEnd = phase ? sliceIters : half;

  short8 aq = *(const short8*)(qT + (size_t)(n0 + 16 * w + l15) * DQ + 8 * quad);

  floatx4 acc[4][4];
  float lsum[4];
  const size_t basep = ((size_t)s * NT + nt) * 256;

  if (phase == 0) {
#pragma unroll
    for (int a2 = 0; a2 < 4; ++a2)
#pragma unroll
      for (int b2 = 0; b2 < 4; ++b2)
        acc[a2][b2] = (floatx4){0.f, 0.f, 0.f, 0.f};
#pragma unroll
    for (int r = 0; r < 4; ++r) lsum[r] = 0.f;
  } else {
    // reload phase-0 partials (bf16 acc + per-row lsum; only l15==0 seeds
    // lsum so the final 16-lane reduction stays correct)
#pragma unroll
    for (int a2 = 0; a2 < 4; ++a2)
#pragma unroll
      for (int b2 = 0; b2 < 4; ++b2)
#pragma unroll
        for (int r = 0; r < 4; ++r) {
          const int c  = cw + a2 * 16 + 4 * quad + r;
          const int nl = b2 * 16 + l15;
          acc[a2][b2][r] = bf2f(Opart[(basep + c) * 64 + nl]);
        }
#pragma unroll
    for (int r = 0; r < 4; ++r) {
      const float lv = lpart[(size_t)s * N + n0 + 16 * w + 4 * quad + r];
      lsum[r] = (l15 == 0) ? lv : 0.f;
    }
  }

  const floatx4 z4 = {0.f, 0.f, 0.f, 0.f};

  for (int it = itBeg; it < itEnd; ++it) {
    const int m0 = mbase + it * 32;

    short8 kb0 = *(const short8*)(kT + (size_t)(m0 + l15) * DQ + 8 * quad);
    short8 kb1 = *(const short8*)(kT + (size_t)(m0 + 16 + l15) * DQ + 8 * quad);
    floatx4 s0 = __builtin_amdgcn_mfma_f32_16x16x32_bf16(aq, kb0, z4, 0, 0, 0);
    floatx4 s1 = __builtin_amdgcn_mfma_f32_16x16x32_bf16(aq, kb1, z4, 0, 0, 0);

    const ushort_t* vb = vG + (size_t)m0 + 8 * quad;
    short8 av0 = *(const short8*)(vb + (size_t)(cw +  0 + l15) * N);
    short8 av1 = *(const short8*)(vb + (size_t)(cw + 16 + l15) * N);
    short8 av2 = *(const short8*)(vb + (size_t)(cw + 32 + l15) * N);
    short8 av3 = *(const short8*)(vb + (size_t)(cw + 48 + l15) * N);

    ushort_t* pb = &Pb[it & 1][0][0];
#pragma unroll
    for (int r = 0; r < 4; ++r) {
      float p0 = exp2f(s0[r]);
      float p1 = exp2f(s1[r]);
      lsum[r] += p0 + p1;
      const int row = 16 * w + 4 * quad + r;
      pb[row * 36 + l15]      = f2bf_fast(p0);
      pb[row * 36 + 16 + l15] = f2bf_fast(p1);
    }
    __syncthreads();

#pragma unroll
    for (int b2 = 0; b2 < 4; ++b2) {
      const ushort_t* pr = pb + (b2 * 16 + l15) * 36 + 8 * quad;
      union { uint2 u2[2]; short8 v; } u;
      u.u2[0] = *(const uint2*)(pr);
      u.u2[1] = *(const uint2*)(pr + 4);
      const short8 pf = u.v;
      acc[0][b2] = __builtin_amdgcn_mfma_f32_16x16x32_bf16(av0, pf, acc[0][b2], 0, 0, 0);
      acc[1][b2] = __builtin_amdgcn_mfma_f32_16x16x32_bf16(av1, pf, acc[1][b2], 0, 0, 0);
      acc[2][b2] = __builtin_amdgcn_mfma_f32_16x16x32_bf16(av2, pf, acc[2][b2], 0, 0, 0);
      acc[3][b2] = __builtin_amdgcn_mfma_f32_16x16x32_bf16(av3, pf, acc[3][b2], 0, 0, 0);
    }
  }

  // sumexp: reduce over the 16 lanes sharing a quad
#pragma unroll
  for (int r = 0; r < 4; ++r) {
    float v = lsum[r];
    v += __shfl_xor(v, 1);
    v += __shfl_xor(v, 2);
    v += __shfl_xor(v, 4);
    v += __shfl_xor(v, 8);
    lsum[r] = v;
  }
  if (l15 == 0) {
#pragma unroll
    for (int r = 0; r < 4; ++r)
      lpart[(size_t)s * N + n0 + 16 * w + 4 * quad + r] = lsum[r];
  }

  // store O^T partial, layout [s][nt64][c:256][n:64]
#pragma unroll
  for (int a2 = 0; a2 < 4; ++a2)
#pragma unroll
    for (int b2 = 0; b2 < 4; ++b2)
#pragma unroll
      for (int r = 0; r < 4; ++r) {
        const int c  = cw + a2 * 16 + 4 * quad + r;
        const int nl = b2 * 16 + l15;
        Opart[(basep + c) * 64 + nl] = f2bf(acc[a2][b2][r]);
      }
}

// ---------------------------------------------------------------------------
// Kernel 3: fused combine + gate-exp.  UNCHANGED (control).
// ---------------------------------------------------------------------------
template<int NSL>
__global__ __launch_bounds__(1024) void cco_kernel(
    const ushort_t* __restrict__ Opart, const float* __restrict__ lpart,
    float* __restrict__ e_buf, float* __restrict__ sumExp)
{
  const int nt = blockIdx.x;
  const int t = threadIdx.x;
  const int n = t & 63, ci = t >> 6;   // ci in [0,16)
  float mx = -3.4e38f, sm = 0.f;
#pragma unroll
  for (int k = 0; k < 16; ++k) {
    const int c = ci * 16 + k;
    float val = 0.f;
#pragma unroll
    for (int s2 = 0; s2 < NSL; ++s2)
      val += bf2f(Opart[(((size_t)s2 * NT + nt) * 256 + c) * 64 + n]);
    mx = fmaxf(mx, val);
    sm += val;
  }
  __shared__ float rmx[16][64], rsm[16][64];
  rmx[ci][n] = mx; rsm[ci][n] = sm;
  __syncthreads();
  if (t < 64) {
    float m = rmx[0][t], s = rsm[0][t];
#pragma unroll
    for (int g = 1; g < 16; ++g) { m = fmaxf(m, rmx[g][t]); s += rsm[g][t]; }
    float l = 0.f;
#pragma unroll
    for (int s3 = 0; s3 < NSL; ++s3) l += lpart[(size_t)s3 * N + nt * 64 + t];
    const float oc = (m + s * (1.0f / 256.0f)) / l;
    const float ev = exp2f(oc * (0.0625f * LOG2E));
    e_buf[nt * 64 + t] = ev;
    float vs = ev;
    vs += __shfl_xor(vs, 1);  vs += __shfl_xor(vs, 2);
    vs += __shfl_xor(vs, 4);  vs += __shfl_xor(vs, 8);
    vs += __shfl_xor(vs, 16); vs += __shfl_xor(vs, 32);
    if (t == 0) atomicAdd(sumExp, vs);
  }
}

// ---------------------------------------------------------------------------
// Kernel 4: final 1x1 conv via bf16 MFMA + fp32 epilogue.  UNCHANGED.
// ---------------------------------------------------------------------------
__global__ __launch_bounds__(256) void final_mfma(
    const float* __restrict__ x, const float* __restrict__ W6,
    const float* __restrict__ b6, const float* __restrict__ gamma,
    const float* __restrict__ e_buf, const float* __restrict__ sumExp,
    float* __restrict__ out)
{
  __shared__ ushort_t xbT[64][XBT_STRIDE];
  const int t = threadIdx.x;
  const int n0 = blockIdx.x * 64;
  const int w = t >> 6, lane = t & 63;
  const int quad = lane >> 4, l15 = lane & 15;

  stage_x_tile(x, n0, t, xbT);
  __syncthreads();

  const int obase = blockIdx.y * 64 + w * 16;
  const float* Arow = W6 + (size_t)(obase + l15) * CIN;

  floatx4 acc[4];
#pragma unroll
  for (int b2 = 0; b2 < 4; ++b2) acc[b2] = (floatx4){0.f, 0.f, 0.f, 0.f};

#pragma unroll
  for (int ks = 0; ks < 8; ++ks) {
    const short8 af = mk_bf16x8(Arow + ks * 32 + 8 * quad);
#pragma unroll
    for (int b2 = 0; b2 < 4; ++b2) {
      const short8 bf = *(const short8*)&xbT[b2 * 16 + l15][ks * 32 + 8 * quad];
      acc[b2] = __builtin_amdgcn_mfma_f32_16x16x32_bf16(af, bf, acc[b2], 0, 0, 0);
    }
  }

  const float g1 = 1.0f + gamma[0];
  const float inv = 1.0f / sumExp[0];
#pragma unroll
  for (int b2 = 0; b2 < 4; ++b2) {
    const int n = n0 + b2 * 16 + l15;
    const float xc = e_buf[n] * inv;
#pragma unroll
    for (int r = 0; r < 4; ++r) {
      const int o = obase + 4 * quad + r;
      const float xv = x[(size_t)o * N + n];
      out[(size_t)o * N + n] = xv + g1 * (xc * acc[b2][r] + b6[o]);
    }
  }
}

// ---------------------------------------------------------------------------
extern "C" void kernel_launch(void* const* d_in, const int* in_sizes, int n_in,
                              void* d_out, int out_size, void* d_ws, size_t ws_size,
                              hipStream_t stream)
{
  const float* x     = (const float*)d_in[0];
  const float* Wq    = (const float*)d_in[1];
  const float* bq    = (const float*)d_in[2];
  const float* Wk    = (const float*)d_in[3];
  const float* bk    = (const float*)d_in[4];
  const float* Wv    = (const float*)d_in[5];
  const float* bv    = (const float*)d_in[6];
  const float* W6    = (const float*)d_in[7];
  const float* b6    = (const float*)d_in[8];
  const float* gamma = (const float*)d_in[9];
  float* out = (float*)d_out;

  // nsl = 7 -> 1008 attn blocks per phase = one co-residency round at 4/CU.
  const size_t fixed = (size_t)N * DQ * 2 * 2        // qT,kT
                     + (size_t)CIN * N * 2            // vG
                     + (size_t)N * 4                  // e_buf
                     + 256;                           // sumExp (+pad)
  int nsl = 7;
  size_t need = fixed + (size_t)nsl * NT * 256 * 64 * 2 + (size_t)nsl * N * 4;
  if (ws_size < need) nsl = 4;
  const int totIters = N / 32;                        // 288
  const int base = totIters / nsl;
  const int rem  = totIters % nsl;

  char* ws = (char*)d_ws;
  const size_t OFF_QT = 0;
  const size_t OFF_KT = OFF_QT + (size_t)N * DQ * 2;
  const size_t OFF_V  = OFF_KT + (size_t)N * DQ * 2;
  const size_t OFF_OP = OFF_V  + (size_t)CIN * N * 2;
  const size_t OFF_LP = OFF_OP + (size_t)nsl * NT * 256 * 64 * 2;
  const size_t OFF_EB = OFF_LP + (size_t)nsl * N * 4;
  const size_t OFF_SE = OFF_EB + (size_t)N * 4;

  ushort_t* qT     = (ushort_t*)(ws + OFF_QT);
  ushort_t* kT     = (ushort_t*)(ws + OFF_KT);
  ushort_t* vG     = (ushort_t*)(ws + OFF_V);
  ushort_t* Opart  = (ushort_t*)(ws + OFF_OP);
  float*    lpart  = (float*)(ws + OFF_LP);
  float*    e_buf  = (float*)(ws + OFF_EB);
  float*    sumExp = (float*)(ws + OFF_SE);

  qkv_mfma<<<dim3(NT, 5), 256, 0, stream>>>(x, Wq, bq, Wk, bk, Wv, bv, qT, kT, vG, sumExp);
  attn_kernel<<<dim3(NT, nsl), 256, 0, stream>>>(qT, kT, vG, Opart, lpart, base, rem, 0);
  attn_kernel<<<dim3(NT, nsl), 256, 0, stream>>>(qT, kT, vG, Opart, lpart, base, rem, 1);
  if (nsl == 7) cco_kernel<7><<<NT, 1024, 0, stream>>>(Opart, lpart, e_buf, sumExp);
  else          cco_kernel<4><<<NT, 1024, 0, stream>>>(Opart, lpart, e_buf, sumExp);
  final_mfma<<<dim3(NT, 4), 256, 0, stream>>>(x, W6, b6, gamma, e_buf, sumExp, out);
}